// Round 6
// baseline (229.706 us; speedup 1.0000x reference)
//
#include <hip/hip_runtime.h>

#define SIGMA_INV 1.0e4f          // 1/SIGMA
#define GAMMA_INV 1.0e4f          // 1/GAMMA
#define ZNEAR 1.0f
#define ZFAR 100.0f
#define EPSV 1e-10f

constexpr int KF = 8;
constexpr int NPIX = 4 * 512 * 512;
constexpr int NPIX2 = NPIX / 2;
constexpr int NFACES = 200000;
// Dropped-slot relative weight <= e^LOG_CUT; worst-case amplification
// (prob ratio ~150 x normalize ~32x) -> ~5e-4, under the 3.9e-3 baseline.
#define LOG_CUT (-16.0f)
#define ZWIN (16.0f / GAMMA_INV)
// delta = exp(-zmax*1e4) < e^-100 ~ 0 when zmax > 0.01: single-survivor
// pixels then have rgb == n exactly (prob cancels) -> skip dists + exps.
#define ZMAX_SAFE 0.01f

// Native vector types for inline-asm register tuples (HIP's int4/float4 are
// structs -> not valid asm "v" tuple operands).
typedef int      i32x4 __attribute__((ext_vector_type(4)));
typedef float    f32x4 __attribute__((ext_vector_type(4)));
typedef unsigned u32x4 __attribute__((ext_vector_type(4)));
typedef float    f32x2 __attribute__((ext_vector_type(2), aligned(4)));

// ---------------------------------------------------------------------------
// Kernel 1: pack the 3 vertex normals of each face into ONE uint4 (16 B).
// 9 components x 14-bit fixed point. Table = 3.2 MB -> L2-resident.
// ---------------------------------------------------------------------------
__global__ __launch_bounds__(256) void pack_face_normals14(
    const int*   __restrict__ faces,   // (F,3)
    const float* __restrict__ vnorm,   // (V,3)
    uint4*       __restrict__ fn,      // (F) packed
    int F)
{
    const int f = blockIdx.x * blockDim.x + threadIdx.x;
    if (f >= F) return;
    const int v[3] = { faces[f * 3 + 0], faces[f * 3 + 1], faces[f * 3 + 2] };

    unsigned long long lo = 0ull, hi = 0ull;
    int i = 0;
#pragma unroll
    for (int t = 0; t < 3; ++t) {
#pragma unroll
        for (int c = 0; c < 3; ++c, ++i) {
            const float x = vnorm[(size_t)v[t] * 3 + c];
            const unsigned long long code = (unsigned long long)(unsigned)
                __float2int_rn(fminf(fmaxf(x, -1.0f), 1.0f) * 8191.5f + 8191.5f);
            const int bp = 14 * i;
            if (bp < 64) {
                lo |= code << bp;
                if (bp > 50) hi |= code >> (64 - bp);
            } else {
                hi |= code << (bp - 64);
            }
        }
    }
    uint4 q;
    q.x = (unsigned)(lo & 0xFFFFFFFFull);
    q.y = (unsigned)(lo >> 32);
    q.z = (unsigned)(hi & 0xFFFFFFFFull);
    q.w = (unsigned)(hi >> 32);
    fn[f] = q;
}

__device__ __forceinline__ float dec14(const unsigned* w, int i) {
    const int bp = 14 * i;
    const int j = bp >> 5;
    const int off = bp & 31;
    unsigned long long u = (unsigned long long)w[j];
    if (j < 3) u |= (unsigned long long)w[j + 1] << 32;
    const unsigned code = (unsigned)(u >> off) & 0x3FFFu;
    return fmaf((float)code, 2.0f / 16383.0f, -1.0f);
}

// Fast/heavy accumulate + epilogue + store for one pixel. All loop indices
// compile-time after inlining (static register indexing, no scratch).
__device__ __forceinline__ void shade_tail(
    int p, const int* f, const float* zinv, float zmax,
    bool has, unsigned rem2, bool heavy, float zsel, size_t sidx,
    u32x4 q, f32x2 b01,
    const float* __restrict__ bary, const float* __restrict__ dists,
    const uint4* __restrict__ fn, float* __restrict__ out)
{
    unsigned w[4] = { q[0], q[1], q[2], q[3] };
    const float b0 = b01[0];
    const float b1 = b01[1];
    const float b2 = 1.0f - b0 - b1;   // reference normalizes bary to sum=1
    const float nx = b0 * dec14(w, 0) + b1 * dec14(w, 3) + b2 * dec14(w, 6);
    const float ny = b0 * dec14(w, 1) + b1 * dec14(w, 4) + b2 * dec14(w, 7);
    const float nz = b0 * dec14(w, 2) + b1 * dec14(w, 5) + b2 * dec14(w, 8);

    float accx = 0.0f, accy = 0.0f, accz = 0.0f, wtot = 0.0f;
    if (has) {
        if (!heavy) {
            // single survivor, delta ~ 0: rgb == n (prob cancels).
            accx = nx; accy = ny; accz = nz; wtot = 1.0f;
        } else {
            // exact path (~6% of lanes): needs prob + exp weights.
            const float dv0 = dists[sidx];
            const float pr0 = 1.0f / (1.0f + __expf(dv0 * SIGMA_INV));
            const float wg0 = pr0 * __expf((zsel - zmax) * GAMMA_INV);
            wtot = wg0;
            accx = wg0 * nx; accy = wg0 * ny; accz = wg0 * nz;

            while (rem2) {
                int ks = 0, gs = 0;
                float zs = 0.0f;
#pragma unroll
                for (int k = KF - 1; k >= 0; --k) {
                    if (rem2 & (1u << k)) { ks = k; gs = f[k]; zs = zinv[k]; }
                }
                rem2 &= rem2 - 1u;

                const size_t s2 = (size_t)p * KF + (size_t)ks;
                const uint4 q2 = fn[gs];
                const f32x2 bb = *reinterpret_cast<const f32x2*>(bary + s2 * 3);
                const float dvs = dists[s2];

                unsigned w2[4] = { q2.x, q2.y, q2.z, q2.w };
                const float c0 = bb[0];
                const float c1 = bb[1];
                const float c2 = 1.0f - c0 - c1;
                const float mx = c0 * dec14(w2, 0) + c1 * dec14(w2, 3) + c2 * dec14(w2, 6);
                const float my = c0 * dec14(w2, 1) + c1 * dec14(w2, 4) + c2 * dec14(w2, 7);
                const float mz = c0 * dec14(w2, 2) + c1 * dec14(w2, 5) + c2 * dec14(w2, 8);

                const float prob = 1.0f / (1.0f + __expf(dvs * SIGMA_INV));
                const float wgt  = prob * __expf((zs - zmax) * GAMMA_INV);
                wtot += wgt;
                accx = fmaf(wgt, mx, accx);
                accy = fmaf(wgt, my, accy);
                accz = fmaf(wgt, mz, accz);
            }
        }
    }

    const float delta = fmaxf(__expf((EPSV - zmax) * GAMMA_INV), EPSV);
    const float inv_denom = 1.0f / (wtot + delta);
    const float r = (accx + delta) * inv_denom;   // bg = (1,1,1)
    const float g = (accy + delta) * inv_denom;
    const float b = (accz + delta) * inv_denom;

    const float nrm = sqrtf(r * r + g * g + b * b);
    const float invn = 1.0f / fmaxf(nrm, 1e-12f);

    float* o = out + (size_t)p * 3;
    o[0] = fmaf(r * invn, 0.5f, 0.5f);
    o[1] = fmaf(g * invn, 0.5f, 0.5f);
    o[2] = fmaf(b * invn, 0.5f, 0.5f);
}

// ---------------------------------------------------------------------------
// Kernel 2 (R13): R12's lean fetch + R9's MLP. Model (R8-R12 consistent,
// after discovering the "L3-hot replay" rows were WRITE-only counter
// passes): duration ~ HBM fetch bytes / achieved_BW(queue depth). R12 cut
// bytes 136->118 MB -> -13% time at ~2.0 TB/s; R9 showed ~2.6 TB/s achieved
// with 2px/thread + batched windows (but paid +68 MB universal-2nd-survivor
// fetch). Here: 2 pixels/thread (split halves, streams stay coalesced),
// BOTH pixels' 8 stream loads in one monolithic sc0 asm window, both
// pixels' survivor gathers (fn x2 + bary x2) in a second window; heavy path
// stays lazy (no fetch inflation). Fetch stays ~118 MB (~ the 114 MB
// algorithmic floor); queue depth per thread doubles.
// ---------------------------------------------------------------------------
__global__ __launch_bounds__(256) void normal_shader_q14_mlp2(
    const int*   __restrict__ p2f,    // (N,H,W,K)
    const float* __restrict__ bary,   // (N,H,W,K,3)
    const float* __restrict__ zbuf,   // (N,H,W,K)
    const float* __restrict__ dists,  // (N,H,W,K)
    const uint4* __restrict__ fn,     // (F) packed face normals
    float*       __restrict__ out)    // (N,H,W,3)
{
    const int t = blockIdx.x * blockDim.x + threadIdx.x;
    if (t >= NPIX2) return;
    const int p0 = t;
    const int p1 = t + NPIX2;

    // ---- window 1: 8 coalesced stream loads (both pixels), sc0 ----
    const int*   pf0 = p2f + (size_t)p0 * KF;
    const float* zz0 = zbuf + (size_t)p0 * KF;
    const int*   pf1 = p2f + (size_t)p1 * KF;
    const float* zz1 = zbuf + (size_t)p1 * KF;

    i32x4 fa0, fb0, fa1, fb1;
    f32x4 za0, zb0, za1, zb1;
    asm volatile(
        "global_load_dwordx4 %0, %8, off sc0\n\t"
        "global_load_dwordx4 %1, %9, off sc0\n\t"
        "global_load_dwordx4 %2, %10, off sc0\n\t"
        "global_load_dwordx4 %3, %11, off sc0\n\t"
        "global_load_dwordx4 %4, %12, off sc0\n\t"
        "global_load_dwordx4 %5, %13, off sc0\n\t"
        "global_load_dwordx4 %6, %14, off sc0\n\t"
        "global_load_dwordx4 %7, %15, off sc0\n\t"
        "s_waitcnt vmcnt(0)"
        : "=&v"(fa0), "=&v"(fb0), "=&v"(za0), "=&v"(zb0),
          "=&v"(fa1), "=&v"(fb1), "=&v"(za1), "=&v"(zb1)
        : "v"(pf0), "v"(pf0 + 4), "v"(zz0), "v"(zz0 + 4),
          "v"(pf1), "v"(pf1 + 4), "v"(zz1), "v"(zz1 + 4)
        : "memory");

    int f0[KF] = {fa0[0], fa0[1], fa0[2], fa0[3], fb0[0], fb0[1], fb0[2], fb0[3]};
    int f1[KF] = {fa1[0], fa1[1], fa1[2], fa1[3], fb1[0], fb1[1], fb1[2], fb1[3]};
    float zv0[KF] = {za0[0], za0[1], za0[2], za0[3], zb0[0], zb0[1], zb0[2], zb0[3]};
    float zv1[KF] = {za1[0], za1[1], za1[2], za1[3], zb1[0], zb1[1], zb1[2], zb1[3]};

    // ---- z_inv + max + survivor mask, both pixels ----
    float zinv0[KF], zinv1[KF];
    float zmax0 = EPSV, zmax1 = EPSV;
#pragma unroll
    for (int k = 0; k < KF; ++k) {
        const float zi0 = (f0[k] >= 0) ? (ZFAR - zv0[k]) * (1.0f / (ZFAR - ZNEAR)) : 0.0f;
        const float zi1 = (f1[k] >= 0) ? (ZFAR - zv1[k]) * (1.0f / (ZFAR - ZNEAR)) : 0.0f;
        zinv0[k] = zi0; zinv1[k] = zi1;
        zmax0 = fmaxf(zmax0, zi0);
        zmax1 = fmaxf(zmax1, zi1);
    }
    const float zcut0 = zmax0 - ZWIN;
    const float zcut1 = zmax1 - ZWIN;
    unsigned rem0 = 0u, rem1 = 0u;
#pragma unroll
    for (int k = 0; k < KF; ++k) {
        if (f0[k] >= 0 && zinv0[k] > zcut0) rem0 |= (1u << k);
        if (f1[k] >= 0 && zinv1[k] > zcut1) rem1 |= (1u << k);
    }

    // ---- first survivor per pixel (unrolled cndmask chains) ----
    int ks0 = 0, fs0 = 0; float zs0 = 0.0f;
#pragma unroll
    for (int k = KF - 1; k >= 0; --k)
        if (rem0 & (1u << k)) { ks0 = k; fs0 = f0[k]; zs0 = zinv0[k]; }
    const bool has0 = (rem0 != 0u);
    const unsigned rem20 = rem0 & (rem0 - 1u);
    const bool heavy0 = (rem20 != 0u) || (zmax0 <= ZMAX_SAFE);

    int ks1 = 0, fs1 = 0; float zs1 = 0.0f;
#pragma unroll
    for (int k = KF - 1; k >= 0; --k)
        if (rem1 & (1u << k)) { ks1 = k; fs1 = f1[k]; zs1 = zinv1[k]; }
    const bool has1 = (rem1 != 0u);
    const unsigned rem21 = rem1 & (rem1 - 1u);
    const bool heavy1 = (rem21 != 0u) || (zmax1 <= ZMAX_SAFE);

    // ---- window 2: survivor gathers for both pixels, sc0 ----
    const size_t sidx0 = (size_t)p0 * KF + (size_t)ks0;
    const size_t sidx1 = (size_t)p1 * KF + (size_t)ks1;
    const unsigned* qp0 = reinterpret_cast<const unsigned*>(fn + fs0);
    const unsigned* qp1 = reinterpret_cast<const unsigned*>(fn + fs1);
    const float*    bp0 = bary + sidx0 * 3;
    const float*    bp1 = bary + sidx1 * 3;

    u32x4 q0, q1;
    f32x2 b010, b011;
    asm volatile(
        "global_load_dwordx4 %0, %4, off sc0\n\t"
        "global_load_dwordx2 %1, %5, off sc0\n\t"
        "global_load_dwordx4 %2, %6, off sc0\n\t"
        "global_load_dwordx2 %3, %7, off sc0\n\t"
        "s_waitcnt vmcnt(0)"
        : "=&v"(q0), "=&v"(b010), "=&v"(q1), "=&v"(b011)
        : "v"(qp0), "v"(bp0), "v"(qp1), "v"(bp1)
        : "memory");

    // ---- decode + accumulate + epilogue + store, both pixels ----
    shade_tail(p0, f0, zinv0, zmax0, has0, rem20, heavy0, zs0, sidx0,
               q0, b010, bary, dists, fn, out);
    shade_tail(p1, f1, zinv1, zmax1, has1, rem21, heavy1, zs1, sidx1,
               q1, b011, bary, dists, fn, out);
}

// ---------------------------------------------------------------------------
// Fallback (R1 kernel) in case d_ws is too small for the 3.2 MB table.
// ---------------------------------------------------------------------------
__global__ __launch_bounds__(256) void normal_shader_direct(
    const int*   __restrict__ p2f,
    const float* __restrict__ bary,
    const float* __restrict__ zbuf,
    const float* __restrict__ dists,
    const float* __restrict__ vnorm,
    const int*   __restrict__ faces,
    float*       __restrict__ out)
{
    const int p = blockIdx.x * blockDim.x + threadIdx.x;
    if (p >= NPIX) return;

    const int4* pf4 = reinterpret_cast<const int4*>(p2f + (size_t)p * KF);
    int4 fa = pf4[0], fb = pf4[1];
    int f[KF] = {fa.x, fa.y, fa.z, fa.w, fb.x, fb.y, fb.z, fb.w};

    const float4* z4 = reinterpret_cast<const float4*>(zbuf + (size_t)p * KF);
    float4 za = z4[0], zb = z4[1];
    float zv[KF] = {za.x, za.y, za.z, za.w, zb.x, zb.y, zb.z, zb.w};

    const float4* d4 = reinterpret_cast<const float4*>(dists + (size_t)p * KF);
    float4 da = d4[0], db = d4[1];
    float dv[KF] = {da.x, da.y, da.z, da.w, db.x, db.y, db.z, db.w};

    const float4* b4 = reinterpret_cast<const float4*>(bary + (size_t)p * KF * 3);
    float bc[KF * 3];
#pragma unroll
    for (int i = 0; i < 6; ++i) {
        float4 t = b4[i];
        bc[4 * i + 0] = t.x; bc[4 * i + 1] = t.y;
        bc[4 * i + 2] = t.z; bc[4 * i + 3] = t.w;
    }

    float zinv[KF], prob[KF];
    float zmax = EPSV;
#pragma unroll
    for (int k = 0; k < KF; ++k) {
        const bool m = f[k] >= 0;
        const float zi = m ? (ZFAR - zv[k]) * (1.0f / (ZFAR - ZNEAR)) : 0.0f;
        const float pr = m ? 1.0f / (1.0f + __expf(dv[k] * SIGMA_INV)) : 0.0f;
        zinv[k] = zi;
        prob[k] = pr;
        zmax = fmaxf(zmax, zi);
    }

    float accx = 0.0f, accy = 0.0f, accz = 0.0f, wtot = 0.0f;
#pragma unroll
    for (int k = 0; k < KF; ++k) {
        const int idx = f[k] < 0 ? 0 : f[k];
        const int i3 = idx * 3;
        const int v0 = faces[i3 + 0];
        const int v1 = faces[i3 + 1];
        const int v2 = faces[i3 + 2];
        const float b0 = bc[k * 3 + 0];
        const float b1 = bc[k * 3 + 1];
        const float b2 = bc[k * 3 + 2];
        const float* n0 = vnorm + (size_t)v0 * 3;
        const float* n1 = vnorm + (size_t)v1 * 3;
        const float* n2 = vnorm + (size_t)v2 * 3;
        const float nx = b0 * n0[0] + b1 * n1[0] + b2 * n2[0];
        const float ny = b0 * n0[1] + b1 * n1[1] + b2 * n2[1];
        const float nz = b0 * n0[2] + b1 * n1[2] + b2 * n2[2];
        const float wgt = prob[k] * __expf((zinv[k] - zmax) * GAMMA_INV);
        wtot += wgt;
        accx = fmaf(wgt, nx, accx);
        accy = fmaf(wgt, ny, accy);
        accz = fmaf(wgt, nz, accz);
    }

    const float delta = fmaxf(__expf((EPSV - zmax) * GAMMA_INV), EPSV);
    const float inv_denom = 1.0f / (wtot + delta);
    const float r = (accx + delta) * inv_denom;
    const float g = (accy + delta) * inv_denom;
    const float b = (accz + delta) * inv_denom;

    const float nrm = sqrtf(r * r + g * g + b * b);
    const float invn = 1.0f / fmaxf(nrm, 1e-12f);

    float* o = out + (size_t)p * 3;
    o[0] = fmaf(r * invn, 0.5f, 0.5f);
    o[1] = fmaf(g * invn, 0.5f, 0.5f);
    o[2] = fmaf(b * invn, 0.5f, 0.5f);
}

extern "C" void kernel_launch(void* const* d_in, const int* in_sizes, int n_in,
                              void* d_out, int out_size, void* d_ws, size_t ws_size,
                              hipStream_t stream) {
    const int*   p2f   = (const int*)d_in[0];
    const float* bary  = (const float*)d_in[1];
    const float* zbuf  = (const float*)d_in[2];
    const float* dists = (const float*)d_in[3];
    const float* vnorm = (const float*)d_in[4];
    const int*   faces = (const int*)d_in[5];
    float* out = (float*)d_out;

    const int threads = 256;
    const size_t fn_bytes = (size_t)NFACES * sizeof(uint4);  // 3.2 MB

    if (ws_size >= fn_bytes) {
        uint4* fn = (uint4*)d_ws;
        pack_face_normals14<<<(NFACES + threads - 1) / threads, threads, 0, stream>>>(
            faces, vnorm, fn, NFACES);
        normal_shader_q14_mlp2<<<(NPIX2 + threads - 1) / threads, threads, 0, stream>>>(
            p2f, bary, zbuf, dists, fn, out);
    } else {
        normal_shader_direct<<<(NPIX + threads - 1) / threads, threads, 0, stream>>>(
            p2f, bary, zbuf, dists, vnorm, faces, out);
    }
}